// Round 5
// baseline (1102.975 us; speedup 1.0000x reference)
//
#include <hip/hip_runtime.h>
#include <math.h>

#define SS 2048
#define BB 32
#define HH 1024
#define OCH 16           // o-chunks for split-K vmat
#define OLEN (HH/OCH)    // 64 o per chunk
#define NYB (SS/16)      // 128 score blocks per b (16 s-rows per block)
#define CNT_STRIDE 16    // ints between per-b counters (64 B, own cache line)

typedef float v4f __attribute__((ext_vector_type(4)));  // clang-native float4

// Kernel 1 (split-K): vpart[oc][b][h] = sum_{o in chunk} hidden[b,o]*W[o,h]
// Also zeroes the per-b completion counters used by the fused score kernel
// (safe: K1 fully completes before K2 starts, stream order + runtime cache
// maintenance guarantee visibility).
__global__ __launch_bounds__(256) void vmat_kernel(const float* __restrict__ hidden,
                                                   const float* __restrict__ W,
                                                   float* __restrict__ vpart,
                                                   int* __restrict__ cnt) {
    const int oc = blockIdx.x;
    const int b  = blockIdx.y;
    const int t  = threadIdx.x;
    if (oc == 0 && b == 0 && t < BB) cnt[t * CNT_STRIDE] = 0;

    const float* __restrict__ hrow = hidden + (size_t)b * HH;
    const v4f* __restrict__ Wrow = (const v4f*)W;  // Wrow[o*256 + t]

    v4f acc = (v4f){0.f, 0.f, 0.f, 0.f};
    const int o0 = oc * OLEN;
    #pragma unroll 4
    for (int oo = 0; oo < OLEN; ++oo) {
        const int o = o0 + oo;
        const float hs = hrow[o];               // wave-uniform
        const v4f w = Wrow[(size_t)o * 256 + t];
        acc += hs * w;
    }
    ((v4f*)(vpart + ((size_t)oc * BB + b) * HH))[t] = acc;
}

// Kernel 2 (FUSED fold + score + last-block softmax).
// grid (BB, NYB) = (32,128), block 256 = 4 waves, 4 s-rows per wave.
//  - fold: thread t sums vpart[0..15][b][4t..4t+3] (L2-hot, same order as the
//    old fold kernel -> bit-identical v), stages the row in LDS.
//  - score: identical NT-load body to R3 (NT is +32 us vs plain, R2).
//  - epilogue: after a device release fence, each block bumps cnt[b]; the
//    128th block for b acquires and runs the (unchanged) softmax for row b.
//    No spin-waits: deadlock-free under any dispatch order (G16).
__global__ __launch_bounds__(256, 4) void score_fused_kernel(const float* __restrict__ enc,
                                                             const float* __restrict__ vpart,
                                                             float* __restrict__ out,
                                                             int* __restrict__ cnt) {
    const int b = blockIdx.x;
    const int t = threadIdx.x;
    const int wave = t >> 6;
    const int lane = t & 63;

    __shared__ float vlds[HH];
    __shared__ float redm[4];
    __shared__ float reds[4];
    __shared__ int last;

    // ---- fold (replaces fold_kernel) ----
    {
        v4f facc = (v4f){0.f, 0.f, 0.f, 0.f};
        #pragma unroll
        for (int c = 0; c < OCH; ++c)
            facc += ((const v4f*)(vpart + ((size_t)c * BB + b) * HH))[t];
        ((v4f*)vlds)[t] = facc;
    }
    __syncthreads();

    const v4f v0 = ((const v4f*)vlds)[lane];
    const v4f v1 = ((const v4f*)vlds)[lane + 64];
    const v4f v2 = ((const v4f*)vlds)[lane + 128];
    const v4f v3 = ((const v4f*)vlds)[lane + 192];

    // ---- score (identical to R3 body) ----
    const int s0 = (blockIdx.y * 4 + wave) * 4;       // 4 rows per wave
    const v4f* __restrict__ erow0 =
        (const v4f*)(enc + ((size_t)s0 * BB + b) * HH);
    const size_t sstride = (size_t)BB * HH / 4;       // v4f units between s rows

    v4f e[4][4];
    #pragma unroll
    for (int r = 0; r < 4; ++r) {
        const v4f* __restrict__ p = erow0 + (size_t)r * sstride;
        e[r][0] = __builtin_nontemporal_load(&p[lane]);
        e[r][1] = __builtin_nontemporal_load(&p[lane + 64]);
        e[r][2] = __builtin_nontemporal_load(&p[lane + 128]);
        e[r][3] = __builtin_nontemporal_load(&p[lane + 192]);
    }

    #pragma unroll
    for (int r = 0; r < 4; ++r) {
        float acc = 0.f;
        acc = fmaf(e[r][0].x, v0.x, acc); acc = fmaf(e[r][0].y, v0.y, acc);
        acc = fmaf(e[r][0].z, v0.z, acc); acc = fmaf(e[r][0].w, v0.w, acc);
        acc = fmaf(e[r][1].x, v1.x, acc); acc = fmaf(e[r][1].y, v1.y, acc);
        acc = fmaf(e[r][1].z, v1.z, acc); acc = fmaf(e[r][1].w, v1.w, acc);
        acc = fmaf(e[r][2].x, v2.x, acc); acc = fmaf(e[r][2].y, v2.y, acc);
        acc = fmaf(e[r][2].z, v2.z, acc); acc = fmaf(e[r][2].w, v2.w, acc);
        acc = fmaf(e[r][3].x, v3.x, acc); acc = fmaf(e[r][3].y, v3.y, acc);
        acc = fmaf(e[r][3].z, v3.z, acc); acc = fmaf(e[r][3].w, v3.w, acc);

        #pragma unroll
        for (int off = 32; off >= 1; off >>= 1)
            acc += __shfl_xor(acc, off, 64);

        if (lane == 0) out[(size_t)b * SS + s0 + r] = acc;
    }

    // ---- last-block-per-b softmax (replaces softmax_kernel) ----
    __threadfence();                         // release our 16 scores (agent)
    if (t == 0) last = atomicAdd(&cnt[b * CNT_STRIDE], 1);
    __syncthreads();
    if (last != NYB - 1) return;
    __threadfence();                         // acquire other blocks' scores

    float* __restrict__ row = out + (size_t)b * SS;
    float x[8];
    float m = -INFINITY;
    #pragma unroll
    for (int i = 0; i < 8; ++i) {
        x[i] = row[t + 256 * i];
        m = fmaxf(m, x[i]);
    }
    #pragma unroll
    for (int off = 32; off >= 1; off >>= 1)
        m = fmaxf(m, __shfl_xor(m, off, 64));
    if (lane == 0) redm[wave] = m;
    __syncthreads();
    m = fmaxf(fmaxf(redm[0], redm[1]), fmaxf(redm[2], redm[3]));

    float ssum = 0.f;
    #pragma unroll
    for (int i = 0; i < 8; ++i) {
        x[i] = expf(x[i] - m);
        ssum += x[i];
    }
    #pragma unroll
    for (int off = 32; off >= 1; off >>= 1)
        ssum += __shfl_xor(ssum, off, 64);
    if (lane == 0) reds[wave] = ssum;
    __syncthreads();
    ssum = (reds[0] + reds[1]) + (reds[2] + reds[3]);

    const float inv = 1.0f / ssum;
    #pragma unroll
    for (int i = 0; i < 8; ++i)
        row[t + 256 * i] = x[i] * inv;
}

extern "C" void kernel_launch(void* const* d_in, const int* in_sizes, int n_in,
                              void* d_out, int out_size, void* d_ws, size_t ws_size,
                              hipStream_t stream) {
    const float* hidden = (const float*)d_in[0];   // [B,H]
    const float* enc    = (const float*)d_in[1];   // [S,B,H]
    const float* W      = (const float*)d_in[2];   // [H,H] (out,in)
    // d_in[3] = bias: shifts score[b,:] uniformly -> softmax-invariant, dropped.
    float* out   = (float*)d_out;                  // [B,1,S] flat = [B,S]
    float* vpart = (float*)d_ws;                   // [OCH][B][H] (2 MiB)
    int*   cnt   = (int*)(vpart + (size_t)OCH * BB * HH);  // 32 counters, 64B apart

    vmat_kernel<<<dim3(OCH, BB), 256, 0, stream>>>(hidden, W, vpart, cnt);
    score_fused_kernel<<<dim3(BB, NYB), 256, 0, stream>>>(enc, vpart, out, cnt);
}

// Round 6
// 352.472 us; speedup vs baseline: 3.1293x; 3.1293x over previous
//
#include <hip/hip_runtime.h>
#include <math.h>

#define SS 2048
#define BB 32
#define HH 1024
#define OCH 16           // o-chunks for split-K vmat
#define OLEN (HH/OCH)    // 64 o per chunk
#define NYB (SS/16)      // 128 score blocks per b (16 s-rows per block)

typedef float v4f __attribute__((ext_vector_type(4)));  // clang-native float4

// Kernel 1 (split-K): vpart[oc][b][h] = sum_{o in chunk} hidden[b,o]*W[o,h]
// grid (OCH, BB) = 512 blocks, block 256.
__global__ __launch_bounds__(256) void vmat_kernel(const float* __restrict__ hidden,
                                                   const float* __restrict__ W,
                                                   float* __restrict__ vpart) {
    const int oc = blockIdx.x;
    const int b  = blockIdx.y;
    const int t  = threadIdx.x;
    const float* __restrict__ hrow = hidden + (size_t)b * HH;
    const v4f* __restrict__ Wrow = (const v4f*)W;  // Wrow[o*256 + t]

    v4f acc = (v4f){0.f, 0.f, 0.f, 0.f};
    const int o0 = oc * OLEN;
    #pragma unroll 4
    for (int oo = 0; oo < OLEN; ++oo) {
        const int o = o0 + oo;
        const float hs = hrow[o];               // wave-uniform
        const v4f w = Wrow[(size_t)o * 256 + t];
        acc += hs * w;
    }
    ((v4f*)(vpart + ((size_t)oc * BB + b) * HH))[t] = acc;
}

// Kernel 2 (fold + score, NO cross-block sync — R5's fence epilogue removed).
// grid (BB, NYB) = (32,128), block 256 = 4 waves, 4 s-rows per wave.
//  - fold: thread t sums vpart[0..15][b][4t..4t+3] (L2-hot, same order as the
//    old fold kernel -> bit-identical v), stages row in LDS.
//  - score: identical NT-load body to R3 (NT is +32 us vs plain, R2;
//    grid orientation x=b kept from R3, proven neutral).
// Removes one dispatch boundary vs R3's 4-kernel chain; this round MEASURES
// the per-dispatch-boundary cost g (prediction: dur drops by g+3us).
__global__ __launch_bounds__(256, 4) void score_fused_kernel(const float* __restrict__ enc,
                                                             const float* __restrict__ vpart,
                                                             float* __restrict__ out) {
    const int b = blockIdx.x;
    const int t = threadIdx.x;
    const int wave = t >> 6;
    const int lane = t & 63;

    __shared__ float vlds[HH];

    // ---- fold (replaces fold_kernel; bit-identical summation order) ----
    {
        v4f facc = (v4f){0.f, 0.f, 0.f, 0.f};
        #pragma unroll
        for (int c = 0; c < OCH; ++c)
            facc += ((const v4f*)(vpart + ((size_t)c * BB + b) * HH))[t];
        ((v4f*)vlds)[t] = facc;
    }
    __syncthreads();

    const v4f v0 = ((const v4f*)vlds)[lane];
    const v4f v1 = ((const v4f*)vlds)[lane + 64];
    const v4f v2 = ((const v4f*)vlds)[lane + 128];
    const v4f v3 = ((const v4f*)vlds)[lane + 192];

    // ---- score (identical to R3 body) ----
    const int s0 = (blockIdx.y * 4 + wave) * 4;       // 4 rows per wave
    const v4f* __restrict__ erow0 =
        (const v4f*)(enc + ((size_t)s0 * BB + b) * HH);
    const size_t sstride = (size_t)BB * HH / 4;       // v4f units between s rows

    v4f e[4][4];
    #pragma unroll
    for (int r = 0; r < 4; ++r) {
        const v4f* __restrict__ p = erow0 + (size_t)r * sstride;
        e[r][0] = __builtin_nontemporal_load(&p[lane]);
        e[r][1] = __builtin_nontemporal_load(&p[lane + 64]);
        e[r][2] = __builtin_nontemporal_load(&p[lane + 128]);
        e[r][3] = __builtin_nontemporal_load(&p[lane + 192]);
    }

    #pragma unroll
    for (int r = 0; r < 4; ++r) {
        float acc = 0.f;
        acc = fmaf(e[r][0].x, v0.x, acc); acc = fmaf(e[r][0].y, v0.y, acc);
        acc = fmaf(e[r][0].z, v0.z, acc); acc = fmaf(e[r][0].w, v0.w, acc);
        acc = fmaf(e[r][1].x, v1.x, acc); acc = fmaf(e[r][1].y, v1.y, acc);
        acc = fmaf(e[r][1].z, v1.z, acc); acc = fmaf(e[r][1].w, v1.w, acc);
        acc = fmaf(e[r][2].x, v2.x, acc); acc = fmaf(e[r][2].y, v2.y, acc);
        acc = fmaf(e[r][2].z, v2.z, acc); acc = fmaf(e[r][2].w, v2.w, acc);
        acc = fmaf(e[r][3].x, v3.x, acc); acc = fmaf(e[r][3].y, v3.y, acc);
        acc = fmaf(e[r][3].z, v3.z, acc); acc = fmaf(e[r][3].w, v3.w, acc);

        #pragma unroll
        for (int off = 32; off >= 1; off >>= 1)
            acc += __shfl_xor(acc, off, 64);

        if (lane == 0) out[(size_t)b * SS + s0 + r] = acc;
    }
}

// Kernel 3: in-place softmax over s for each b. grid BB, block 256.
__global__ __launch_bounds__(256) void softmax_kernel(float* __restrict__ out) {
    const int b = blockIdx.x;
    float* __restrict__ row = out + (size_t)b * SS;
    const int tid = threadIdx.x;
    const int wave = tid >> 6;
    const int lane = tid & 63;

    float x[8];
    float m = -INFINITY;
    #pragma unroll
    for (int i = 0; i < 8; ++i) {
        x[i] = row[tid + 256 * i];
        m = fmaxf(m, x[i]);
    }
    #pragma unroll
    for (int off = 32; off >= 1; off >>= 1)
        m = fmaxf(m, __shfl_xor(m, off, 64));

    __shared__ float redm[4];
    __shared__ float reds[4];
    if (lane == 0) redm[wave] = m;
    __syncthreads();
    m = fmaxf(fmaxf(redm[0], redm[1]), fmaxf(redm[2], redm[3]));

    float ssum = 0.f;
    #pragma unroll
    for (int i = 0; i < 8; ++i) {
        x[i] = expf(x[i] - m);
        ssum += x[i];
    }
    #pragma unroll
    for (int off = 32; off >= 1; off >>= 1)
        ssum += __shfl_xor(ssum, off, 64);
    if (lane == 0) reds[wave] = ssum;
    __syncthreads();
    ssum = (reds[0] + reds[1]) + (reds[2] + reds[3]);

    const float inv = 1.0f / ssum;
    #pragma unroll
    for (int i = 0; i < 8; ++i)
        row[tid + 256 * i] = x[i] * inv;
}

extern "C" void kernel_launch(void* const* d_in, const int* in_sizes, int n_in,
                              void* d_out, int out_size, void* d_ws, size_t ws_size,
                              hipStream_t stream) {
    const float* hidden = (const float*)d_in[0];   // [B,H]
    const float* enc    = (const float*)d_in[1];   // [S,B,H]
    const float* W      = (const float*)d_in[2];   // [H,H] (out,in)
    // d_in[3] = bias: shifts score[b,:] uniformly -> softmax-invariant, dropped.
    float* out   = (float*)d_out;                  // [B,1,S] flat = [B,S]
    float* vpart = (float*)d_ws;                   // [OCH][B][H] (2 MiB)

    vmat_kernel<<<dim3(OCH, BB), 256, 0, stream>>>(hidden, W, vpart);
    score_fused_kernel<<<dim3(BB, NYB), 256, 0, stream>>>(enc, vpart, out);
    softmax_kernel<<<BB, 256, 0, stream>>>(out);
}